// Round 2
// baseline (855.149 us; speedup 1.0000x reference)
//
#include <hip/hip_runtime.h>
#include <math.h>

#define CAT    134
#define NRBF   6
#define ADIM   42
#define NBIL   8
#define TILE_E 128
#define WROWS  136   // 134 + 2 zero rows so wave 3's channel block needs no clamping
#define LSTR   36    // LDS row stride in floats: odd granule stride -> <=2-way conflicts
#define NCH    34    // channels per wave (4*34 = 136 >= 134)

// ---------------------------------------------------------------------------
// Kernel 0: pack per-channel epilogue weights: [c][16] = {b_m, W_e row, fw col}
// ---------------------------------------------------------------------------
__global__ __launch_bounds__(256) void prep_kernel(
    const float* __restrict__ b_m, const float* __restrict__ W_e,
    const float* __restrict__ final_w, float* __restrict__ packed)
{
    int c = blockIdx.x * 256 + threadIdx.x;
    if (c < CAT) {
        float* p = packed + c * 16;
        p[0] = b_m[c];
        #pragma unroll
        for (int r = 0; r < NRBF; ++r) p[1 + r] = W_e[c * NRBF + r];
        #pragma unroll
        for (int r = 0; r < NRBF; ++r) p[7 + r] = final_w[r * CAT + c];
        p[13] = 0.f; p[14] = 0.f; p[15] = 0.f;
    }
}

// ---------------------------------------------------------------------------
// Kernel 1: per-angle scalar s_a = dot(a_sbf[a,:], wsum), scatter into sum_s
// ---------------------------------------------------------------------------
__global__ __launch_bounds__(256) void angle_kernel(
    const float* __restrict__ a_sbf, const int* __restrict__ kj_idx,
    const float* __restrict__ W_a, float* __restrict__ sum_s, int A)
{
    __shared__ float wsum[ADIM];
    int tid = threadIdx.x;
    if (tid < ADIM) {
        float s = 0.f;
        #pragma unroll
        for (int b = 0; b < NBIL; ++b) s += W_a[b * ADIM + tid];
        wsum[tid] = s;
    }
    __syncthreads();

    int a = blockIdx.x * 256 + tid;
    if (a >= A) return;

    const float* row = a_sbf + (size_t)a * ADIM;
    float s = 0.f;
    #pragma unroll
    for (int d2 = 0; d2 < ADIM / 2; ++d2) {
        float2 v = *reinterpret_cast<const float2*>(row + d2 * 2);
        s += v.x * wsum[d2 * 2] + v.y * wsum[d2 * 2 + 1];
    }
    atomicAdd(&sum_s[kj_idx[a]], s);
}

// ---------------------------------------------------------------------------
// Kernel 2: tiled VALU GEMM. Block = 128 edges x all 134 channels, K chunked
// by 32. Both operands staged in LDS -> inner loop is ds_read + v_fma only.
// Wave wv owns channels [wv*34, wv*34+34); each lane owns 2 edges.
// ---------------------------------------------------------------------------
template<int CK>
__device__ __forceinline__ void chunk_body(
    int tid, int lane, int cbase, int e0, int k0, int E,
    const float* __restrict__ m_ji, const float* __restrict__ W_m,
    float (&mt)[TILE_E][LSTR], float (&wl)[WROWS][LSTR],
    float (&acc0)[NCH], float (&acc1)[NCH])
{
    constexpr int C2 = CK / 2;
    __syncthreads();   // previous chunk fully consumed before overwrite
    // stage m tile chunk (float2: m rows are only 8B-aligned)
    for (int f2 = tid; f2 < TILE_E * C2; f2 += 256) {
        int r = f2 / C2, c2 = f2 - r * C2;
        int col = k0 + c2 * 2;
        float2 v = make_float2(0.f, 0.f);
        if (e0 + r < E && col < CAT)
            v = *reinterpret_cast<const float2*>(m_ji + (size_t)(e0 + r) * CAT + col);
        mt[r][c2 * 2] = v.x; mt[r][c2 * 2 + 1] = v.y;
    }
    // stage W chunk (rows 134,135 and cols >=134 zero-filled)
    for (int f2 = tid; f2 < WROWS * C2; f2 += 256) {
        int r = f2 / C2, c2 = f2 - r * C2;
        int col = k0 + c2 * 2;
        float2 v = make_float2(0.f, 0.f);
        if (r < CAT && col < CAT)
            v = *reinterpret_cast<const float2*>(W_m + (size_t)r * CAT + col);
        wl[r][c2 * 2] = v.x; wl[r][c2 * 2 + 1] = v.y;
    }
    __syncthreads();

    #pragma unroll 2
    for (int kk = 0; kk < CK; kk += 4) {
        float4 ma = *reinterpret_cast<const float4*>(&mt[lane][kk]);
        float4 mb = *reinterpret_cast<const float4*>(&mt[lane + 64][kk]);
        #pragma unroll
        for (int i = 0; i < NCH; ++i) {
            float4 w = *reinterpret_cast<const float4*>(&wl[cbase + i][kk]);
            acc0[i] += ma.x * w.x + ma.y * w.y + ma.z * w.z + ma.w * w.w;
            acc1[i] += mb.x * w.x + mb.y * w.y + mb.z * w.z + mb.w * w.w;
        }
    }
}

__global__ __launch_bounds__(256) void edge_kernel(
    const float* __restrict__ m_ji, const float* __restrict__ e_rbf,
    const float* __restrict__ W_m, const float* __restrict__ packed,
    const float* __restrict__ sum_s, float* __restrict__ out, int E)
{
    __shared__ float mt[TILE_E][LSTR];   // 18432 B
    __shared__ float wl[WROWS][LSTR];    // 19584 B  -> total 38016 B, 4 blocks/CU

    const int tid   = threadIdx.x;
    const int lane  = tid & 63;
    const int wv    = __builtin_amdgcn_readfirstlane(tid >> 6);
    const int e0    = blockIdx.x * TILE_E;
    const int cbase = wv * NCH;

    float acc0[NCH], acc1[NCH];
    #pragma unroll
    for (int i = 0; i < NCH; ++i) { acc0[i] = 0.f; acc1[i] = 0.f; }

    for (int k0 = 0; k0 < 128; k0 += 32)
        chunk_body<32>(tid, lane, cbase, e0, k0, E, m_ji, W_m, mt, wl, acc0, acc1);
    chunk_body<8>(tid, lane, cbase, e0, 128, E, m_ji, W_m, mt, wl, acc0, acc1);

    // ---- epilogue: silu * transf_e, project onto final_w rows ----
    const int ea = e0 + lane, eb = ea + 64;
    float erbfa[NRBF], erbfb[NRBF];
    #pragma unroll
    for (int r = 0; r < NRBF; ++r) {
        erbfa[r] = (ea < E) ? e_rbf[(size_t)ea * NRBF + r] : 0.f;
        erbfb[r] = (eb < E) ? e_rbf[(size_t)eb * NRBF + r] : 0.f;
    }

    float pr0[NRBF], pr1[NRBF];
    #pragma unroll
    for (int r = 0; r < NRBF; ++r) { pr0[r] = 0.f; pr1[r] = 0.f; }

    #pragma unroll
    for (int i = 0; i < NCH; ++i) {
        const int c = cbase + i;
        if (c < CAT) {   // wave-uniform branch (only wave 3's last 2 skip)
            const float* p = packed + c * 16;
            const float b = p[0];
            const float xa = acc0[i] + b, xb = acc1[i] + b;
            const float sa = xa / (1.f + __expf(-xa));
            const float sb = xb / (1.f + __expf(-xb));
            float tea = 0.f, teb = 0.f;
            #pragma unroll
            for (int r = 0; r < NRBF; ++r) {
                tea += erbfa[r] * p[1 + r];
                teb += erbfb[r] * p[1 + r];
            }
            const float mza = sa * tea, mzb = sb * teb;
            #pragma unroll
            for (int r = 0; r < NRBF; ++r) {
                pr0[r] += p[7 + r] * mza;
                pr1[r] += p[7 + r] * mzb;
            }
        }
    }

    // ---- cross-wave reduction in LDS (reuse wl), scale by sum_s, store ----
    __syncthreads();   // all waves done reading wl
    float* projp = &wl[0][0];   // [4][TILE_E][NRBF] = 3072 floats <= 4896
    #pragma unroll
    for (int r = 0; r < NRBF; ++r) {
        projp[(wv * TILE_E + lane) * NRBF + r]      = pr0[r];
        projp[(wv * TILE_E + lane + 64) * NRBF + r] = pr1[r];
    }
    __syncthreads();

    for (int v = tid; v < TILE_E * NRBF; v += 256) {
        int el = v / NRBF, r = v - el * NRBF;
        float s = projp[v] + projp[768 + v] + projp[1536 + v] + projp[2304 + v];
        int e = e0 + el;
        if (e < E) out[(size_t)e * NRBF + r] = s * sum_s[e];
    }
}

// ---------------------------------------------------------------------------
extern "C" void kernel_launch(void* const* d_in, const int* in_sizes, int n_in,
                              void* d_out, int out_size, void* d_ws, size_t ws_size,
                              hipStream_t stream)
{
    const float* m_ji    = (const float*)d_in[0];
    // d_in[1] nbr_list, d_in[2] angle_list: unused by the reference math
    const float* e_rbf   = (const float*)d_in[3];
    const float* a_sbf   = (const float*)d_in[4];
    const int*   kj_idx  = (const int*)  d_in[5];
    const float* W_m     = (const float*)d_in[6];
    const float* b_m     = (const float*)d_in[7];
    const float* W_e     = (const float*)d_in[8];
    const float* W_a     = (const float*)d_in[9];
    const float* final_w = (const float*)d_in[10];
    float* out = (float*)d_out;

    const int E = in_sizes[0] / CAT;
    const int A = in_sizes[5];

    float* sum_s  = (float*)d_ws;
    float* packed = (float*)((char*)d_ws + (((size_t)E * 4 + 255) & ~(size_t)255));

    hipMemsetAsync(sum_s, 0, (size_t)E * sizeof(float), stream);
    prep_kernel<<<1, 256, 0, stream>>>(b_m, W_e, final_w, packed);
    angle_kernel<<<(A + 255) / 256, 256, 0, stream>>>(a_sbf, kj_idx, W_a, sum_s, A);
    edge_kernel<<<(E + TILE_E - 1) / TILE_E, 256, 0, stream>>>(
        m_ji, e_rbf, W_m, packed, sum_s, out, E);
}

// Round 3
// 414.288 us; speedup vs baseline: 2.0641x; 2.0641x over previous
//
#include <hip/hip_runtime.h>
#include <math.h>

#define CAT    134
#define NRBF   6
#define ADIM   42
#define NBIL   8
#define KPAD   144      // 9 k-steps of 16 (k=134 is the bias column)
#define CHPAD  160      // 5 waves x 32 channels
#define MSTR   152      // mh/ml row stride (shorts): 304 B = 16*19 -> 8 distinct bank slots
#define TSTR   168      // mae_t row stride (shorts): 336 B = 16*21 -> 8 distinct bank slots

typedef __bf16 bf16x8 __attribute__((ext_vector_type(8)));
typedef float  f32x16 __attribute__((ext_vector_type(16)));
typedef float  f32x4  __attribute__((ext_vector_type(4)));

__device__ __forceinline__ unsigned short f32_bf16_rne(float x) {
    union { float f; unsigned u; } v; v.f = x;
    unsigned u = v.u;
    u += 0x7FFFu + ((u >> 16) & 1u);
    return (unsigned short)(u >> 16);
}
__device__ __forceinline__ float bf16_f32(unsigned short h) {
    union { float f; unsigned u; } v; v.u = ((unsigned)h) << 16;
    return v.f;
}

// ---------------------------------------------------------------------------
// prep: split-bf16 pack of W_m(+bias col), W_e (K->16), final_w (rows->16)
// ---------------------------------------------------------------------------
__global__ __launch_bounds__(256) void prep_kernel(
    const float* __restrict__ Wm, const float* __restrict__ bm,
    const float* __restrict__ We, const float* __restrict__ fw,
    unsigned short* __restrict__ WmPh, unsigned short* __restrict__ WmPl,
    unsigned short* __restrict__ WePh, unsigned short* __restrict__ WePl,
    unsigned short* __restrict__ FwPh, unsigned short* __restrict__ FwPl)
{
    int i = blockIdx.x * 256 + threadIdx.x;
    if (i < CHPAD * KPAD) {                       // WmP[160][144]
        int c = i / KPAD, k = i - c * KPAD;
        float v = 0.f;
        if (c < CAT) {
            if (k < CAT) v = Wm[c * CAT + k];
            else if (k == CAT) v = bm[c];         // bias column (pairs with m==1.0)
        }
        unsigned short h = f32_bf16_rne(v);
        WmPh[i] = h; WmPl[i] = f32_bf16_rne(v - bf16_f32(h));
    } else if (i < CHPAD * KPAD + CHPAD * 16) {   // WeP[160][16]
        int j = i - CHPAD * KPAD; int c = j >> 4, r = j & 15;
        float v = (c < CAT && r < NRBF) ? We[c * NRBF + r] : 0.f;
        unsigned short h = f32_bf16_rne(v);
        WePh[j] = h; WePl[j] = f32_bf16_rne(v - bf16_f32(h));
    } else if (i < CHPAD * KPAD + CHPAD * 16 + 16 * CHPAD) {  // FwP[16][160]
        int j = i - CHPAD * KPAD - CHPAD * 16; int r = j / CHPAD, c = j - r * CHPAD;
        float v = (r < NRBF && c < CAT) ? fw[r * CAT + c] : 0.f;
        unsigned short h = f32_bf16_rne(v);
        FwPh[j] = h; FwPl[j] = f32_bf16_rne(v - bf16_f32(h));
    }
}

// ---------------------------------------------------------------------------
// angle: s_a = dot(a_sbf[a,:], colsum(W_a)), scatter-add into sum_s[kj]
// ---------------------------------------------------------------------------
__global__ __launch_bounds__(256) void angle_kernel(
    const float* __restrict__ a_sbf, const int* __restrict__ kj_idx,
    const float* __restrict__ W_a, float* __restrict__ sum_s, int A)
{
    __shared__ float wsum[ADIM];
    int tid = threadIdx.x;
    if (tid < ADIM) {
        float s = 0.f;
        #pragma unroll
        for (int b = 0; b < NBIL; ++b) s += W_a[b * ADIM + tid];
        wsum[tid] = s;
    }
    __syncthreads();

    int a = blockIdx.x * 256 + tid;
    if (a >= A) return;

    const float* row = a_sbf + (size_t)a * ADIM;
    float s = 0.f;
    #pragma unroll
    for (int d2 = 0; d2 < ADIM / 2; ++d2) {
        float2 v = *reinterpret_cast<const float2*>(row + d2 * 2);
        s += v.x * wsum[d2 * 2] + v.y * wsum[d2 * 2 + 1];
    }
    atomicAdd(&sum_s[kj_idx[a]], s);
}

// ---------------------------------------------------------------------------
// edge: full MFMA pipeline (split-bf16):
//   x  = Wm . m   (32x32x16, K=144, bias folded)     -> reg C-layout [c][e]
//   te = We . eb  (32x32x16, K=16)                   -> same layout
//   mae = silu(x)*te  elementwise in regs, split hi/lo -> LDS mae_t[e][c]
//   proj = Fw . mae   (16x16x32, wave w = K-slice of its own channels)
//   out[e][r] = (sum_w proj_partial) * sum_s[e]
// Block = 320 threads (5 waves), 64-edge tile, 2 subtiles of 32 edges.
// ---------------------------------------------------------------------------
__global__ __launch_bounds__(320, 3) void edge_kernel(
    const float* __restrict__ m_ji, const float* __restrict__ e_rbf,
    const unsigned short* __restrict__ WmPh, const unsigned short* __restrict__ WmPl,
    const unsigned short* __restrict__ WePh, const unsigned short* __restrict__ WePl,
    const unsigned short* __restrict__ FwPh, const unsigned short* __restrict__ FwPl,
    const float* __restrict__ sum_s, float* __restrict__ out, int E, int NT)
{
    __shared__ unsigned short mh[64][MSTR];    // 19456 B
    __shared__ unsigned short ml[64][MSTR];    // 19456 B
    __shared__ unsigned short ebh[64][16];     //  2048 B
    __shared__ unsigned short ebl[64][16];     //  2048 B
    __shared__ unsigned short maeh[32][TSTR];  // 10752 B
    __shared__ unsigned short mael[32][TSTR];  // 10752 B
    __shared__ float projp[5][32][8];          //  5120 B   (total 69632 B)

    const int tid = threadIdx.x;
    const int l   = tid & 63;
    const int wv  = __builtin_amdgcn_readfirstlane(tid >> 6);
    const int l31 = l & 31;
    const int hi5 = l >> 5;

    // ---- persistent fragments --------------------------------------------
    bf16x8 wfh[9], wfl[9];
    {
        const unsigned short* base = WmPh + (size_t)(32 * wv + l31) * KPAD + hi5 * 8;
        const unsigned short* basl = WmPl + (size_t)(32 * wv + l31) * KPAD + hi5 * 8;
        #pragma unroll
        for (int ks = 0; ks < 9; ++ks) {
            wfh[ks] = *reinterpret_cast<const bf16x8*>(base + ks * 16);
            wfl[ks] = *reinterpret_cast<const bf16x8*>(basl + ks * 16);
        }
    }
    bf16x8 weh = *reinterpret_cast<const bf16x8*>(WePh + (32 * wv + l31) * 16 + hi5 * 8);
    bf16x8 wel = *reinterpret_cast<const bf16x8*>(WePl + (32 * wv + l31) * 16 + hi5 * 8);
    bf16x8 fwh = *reinterpret_cast<const bf16x8*>(FwPh + (l & 15) * CHPAD + 32 * wv + (l >> 4) * 8);
    bf16x8 fwl = *reinterpret_cast<const bf16x8*>(FwPl + (l & 15) * CHPAD + 32 * wv + (l >> 4) * 8);

    for (int t = blockIdx.x; t < NT; t += gridDim.x) {
        const int e0 = t * 64;

        // ---- stage m tile: fp32 -> bf16 hi/lo, bias col, zero pad --------
        for (int f = tid; f < 64 * (MSTR / 2); f += 320) {
            int r = f / (MSTR / 2), c2 = f - r * (MSTR / 2);
            int k = c2 * 2, e = e0 + r;
            float v0 = 0.f, v1 = 0.f;
            if (k <= CAT - 2) {
                if (e < E) {
                    float2 v = *reinterpret_cast<const float2*>(m_ji + (size_t)e * CAT + k);
                    v0 = v.x; v1 = v.y;
                }
            } else if (k == CAT) {
                v0 = (e < E) ? 1.f : 0.f;   // bias partner column
            }
            unsigned short h0 = f32_bf16_rne(v0), h1 = f32_bf16_rne(v1);
            unsigned short q0 = f32_bf16_rne(v0 - bf16_f32(h0));
            unsigned short q1 = f32_bf16_rne(v1 - bf16_f32(h1));
            *reinterpret_cast<unsigned*>(&mh[r][k]) = (unsigned)h0 | ((unsigned)h1 << 16);
            *reinterpret_cast<unsigned*>(&ml[r][k]) = (unsigned)q0 | ((unsigned)q1 << 16);
        }
        // ---- stage e_rbf tile (split, padded to 16 slots) ----------------
        if (tid < 64) {
            int e = e0 + tid;
            unsigned short hb[8] = {0,0,0,0,0,0,0,0}, lb[8] = {0,0,0,0,0,0,0,0};
            if (e < E) {
                #pragma unroll
                for (int r = 0; r < NRBF; ++r) {
                    float v = e_rbf[(size_t)e * NRBF + r];
                    hb[r] = f32_bf16_rne(v);
                    lb[r] = f32_bf16_rne(v - bf16_f32(hb[r]));
                }
            }
            uint4 ph, pl;
            ph.x = hb[0] | (hb[1] << 16); ph.y = hb[2] | (hb[3] << 16);
            ph.z = hb[4] | (hb[5] << 16); ph.w = hb[6] | (hb[7] << 16);
            pl.x = lb[0] | (lb[1] << 16); pl.y = lb[2] | (lb[3] << 16);
            pl.z = lb[4] | (lb[5] << 16); pl.w = lb[6] | (lb[7] << 16);
            *reinterpret_cast<uint4*>(&ebh[tid][0]) = ph;
            *reinterpret_cast<uint4*>(&ebl[tid][0]) = pl;
            *reinterpret_cast<uint4*>(&ebh[tid][8]) = make_uint4(0, 0, 0, 0);
            *reinterpret_cast<uint4*>(&ebl[tid][8]) = make_uint4(0, 0, 0, 0);
        }
        __syncthreads();

        for (int s = 0; s < 2; ++s) {
            const int erow = 32 * s + l31;

            // ---- MFMA1: x = Wm . m  (+bias), split-bf16 3-product --------
            f32x16 acc  = {0,0,0,0,0,0,0,0,0,0,0,0,0,0,0,0};
            f32x16 acct = {0,0,0,0,0,0,0,0,0,0,0,0,0,0,0,0};
            #pragma unroll
            for (int ks = 0; ks < 9; ++ks) {
                bf16x8 bh = *reinterpret_cast<const bf16x8*>(&mh[erow][ks * 16 + hi5 * 8]);
                bf16x8 bl = *reinterpret_cast<const bf16x8*>(&ml[erow][ks * 16 + hi5 * 8]);
                acc = __builtin_amdgcn_mfma_f32_32x32x16_bf16(wfh[ks], bh, acc, 0, 0, 0);
                acc = __builtin_amdgcn_mfma_f32_32x32x16_bf16(wfl[ks], bh, acc, 0, 0, 0);
                acc = __builtin_amdgcn_mfma_f32_32x32x16_bf16(wfh[ks], bl, acc, 0, 0, 0);
            }
            // ---- te = We . eb -------------------------------------------
            {
                bf16x8 bh = *reinterpret_cast<const bf16x8*>(&ebh[erow][hi5 * 8]);
                bf16x8 bl = *reinterpret_cast<const bf16x8*>(&ebl[erow][hi5 * 8]);
                acct = __builtin_amdgcn_mfma_f32_32x32x16_bf16(weh, bh, acct, 0, 0, 0);
                acct = __builtin_amdgcn_mfma_f32_32x32x16_bf16(wel, bh, acct, 0, 0, 0);
                acct = __builtin_amdgcn_mfma_f32_32x32x16_bf16(weh, bl, acct, 0, 0, 0);
            }

            __syncthreads();   // prev subtile's MFMA3/reduce fully done

            // ---- mae = silu(x)*te, split, write mae_t[e][c] --------------
            #pragma unroll
            for (int q = 0; q < 4; ++q) {
                unsigned long long vh = 0ull, vl = 0ull;
                #pragma unroll
                for (int i = 0; i < 4; ++i) {
                    float x  = acc[q * 4 + i];
                    float sg = x / (1.f + __expf(-x));
                    float mz = sg * acct[q * 4 + i];
                    unsigned short h = f32_bf16_rne(mz);
                    unsigned short w = f32_bf16_rne(mz - bf16_f32(h));
                    vh |= (unsigned long long)h << (16 * i);
                    vl |= (unsigned long long)w << (16 * i);
                }
                int cq = 32 * wv + 8 * q + 4 * hi5;   // 4 consecutive channels
                *reinterpret_cast<unsigned long long*>(&maeh[l31][cq]) = vh;
                *reinterpret_cast<unsigned long long*>(&mael[l31][cq]) = vl;
            }
            __syncthreads();   // mae_t complete

            // ---- MFMA3: proj[r][e], wave w contributes its channel K-slice
            #pragma unroll
            for (int nt = 0; nt < 2; ++nt) {
                f32x4 a3 = {0, 0, 0, 0};
                const int mrow = nt * 16 + (l & 15);
                bf16x8 bh = *reinterpret_cast<const bf16x8*>(&maeh[mrow][32 * wv + (l >> 4) * 8]);
                bf16x8 bl = *reinterpret_cast<const bf16x8*>(&mael[mrow][32 * wv + (l >> 4) * 8]);
                a3 = __builtin_amdgcn_mfma_f32_16x16x32_bf16(fwh, bh, a3, 0, 0, 0);
                a3 = __builtin_amdgcn_mfma_f32_16x16x32_bf16(fwl, bh, a3, 0, 0, 0);
                a3 = __builtin_amdgcn_mfma_f32_16x16x32_bf16(fwh, bl, a3, 0, 0, 0);
                int g4 = l >> 4, es = nt * 16 + (l & 15);
                if (g4 == 0) {
                    *reinterpret_cast<f32x4*>(&projp[wv][es][0]) = a3;   // rows 0-3
                } else if (g4 == 1) {
                    projp[wv][es][4] = a3[0];                            // rows 4-5
                    projp[wv][es][5] = a3[1];
                }
            }
            __syncthreads();   // projp complete

            // ---- cross-wave reduce + scale + store -----------------------
            if (tid < 192) {
                int es = tid / 6, r = tid - es * 6;
                float v = projp[0][es][r] + projp[1][es][r] + projp[2][es][r]
                        + projp[3][es][r] + projp[4][es][r];
                int e = e0 + 32 * s + es;
                if (e < E) out[(size_t)e * NRBF + r] = v * sum_s[e];
            }
        }
        __syncthreads();   // done with mh/ml before next tile's staging
    }
}

// ---------------------------------------------------------------------------
extern "C" void kernel_launch(void* const* d_in, const int* in_sizes, int n_in,
                              void* d_out, int out_size, void* d_ws, size_t ws_size,
                              hipStream_t stream)
{
    const float* m_ji    = (const float*)d_in[0];
    // d_in[1] nbr_list, d_in[2] angle_list: unused by the reference math
    const float* e_rbf   = (const float*)d_in[3];
    const float* a_sbf   = (const float*)d_in[4];
    const int*   kj_idx  = (const int*)  d_in[5];
    const float* W_m     = (const float*)d_in[6];
    const float* b_m     = (const float*)d_in[7];
    const float* W_e     = (const float*)d_in[8];
    const float* W_a     = (const float*)d_in[9];
    const float* final_w = (const float*)d_in[10];
    float* out = (float*)d_out;

    const int E = in_sizes[0] / CAT;
    const int A = in_sizes[5];
    const int NT = (E + 63) / 64;

    // workspace layout
    char* ws = (char*)d_ws;
    float* sum_s = (float*)ws;
    size_t off = ((size_t)E * 4 + 255) & ~(size_t)255;
    unsigned short* WmPh = (unsigned short*)(ws + off); off += CHPAD * KPAD * 2;
    unsigned short* WmPl = (unsigned short*)(ws + off); off += CHPAD * KPAD * 2;
    unsigned short* WePh = (unsigned short*)(ws + off); off += CHPAD * 16 * 2;
    unsigned short* WePl = (unsigned short*)(ws + off); off += CHPAD * 16 * 2;
    unsigned short* FwPh = (unsigned short*)(ws + off); off += 16 * CHPAD * 2;
    unsigned short* FwPl = (unsigned short*)(ws + off); off += 16 * CHPAD * 2;

    hipMemsetAsync(sum_s, 0, (size_t)E * sizeof(float), stream);

    const int prep_n = CHPAD * KPAD + CHPAD * 16 + 16 * CHPAD;
    prep_kernel<<<(prep_n + 255) / 256, 256, 0, stream>>>(
        W_m, b_m, W_e, final_w, WmPh, WmPl, WePh, WePl, FwPh, FwPl);
    angle_kernel<<<(A + 255) / 256, 256, 0, stream>>>(a_sbf, kj_idx, W_a, sum_s, A);
    edge_kernel<<<512, 320, 0, stream>>>(m_ji, e_rbf, WmPh, WmPl, WePh, WePl,
                                         FwPh, FwPl, sum_s, out, E, NT);
}

// Round 4
// 321.568 us; speedup vs baseline: 2.6593x; 1.2883x over previous
//
#include <hip/hip_runtime.h>
#include <math.h>

#define CAT    134
#define NRBF   6
#define ADIM   42
#define NBIL   8
#define KPAD   144      // 9 k-steps of 16 (k=134 is the bias column)
#define CHPAD  160      // 5 waves x 32 channels
#define TSTR   168      // mae row stride in shorts: 336 B (16B-aligned rows, 2-way-max write conflicts)

typedef __bf16 bf16x8 __attribute__((ext_vector_type(8)));
typedef float  f32x16 __attribute__((ext_vector_type(16)));
typedef float  f32x4  __attribute__((ext_vector_type(4)));

__device__ __forceinline__ unsigned short f32_bf16_rne(float x) {
    union { float f; unsigned u; } v; v.f = x;
    unsigned u = v.u;
    u += 0x7FFFu + ((u >> 16) & 1u);
    return (unsigned short)(u >> 16);
}
__device__ __forceinline__ float bf16_f32(unsigned short h) {
    union { float f; unsigned u; } v; v.u = ((unsigned)h) << 16;
    return v.f;
}

// trunc-based split: a = hi + lo with |err| ~ 2^-17 |a|; 3 VALU/value, v_perm-shaped
__device__ __forceinline__ void split_pack(float a, float b, unsigned& ph, unsigned& pl) {
    unsigned ua = __float_as_uint(a), ub = __float_as_uint(b);
    ph = (ua >> 16) | (ub & 0xffff0000u);
    float ra = a - __uint_as_float(ua & 0xffff0000u);
    float rb = b - __uint_as_float(ub & 0xffff0000u);
    pl = (__float_as_uint(ra) >> 16) | (__float_as_uint(rb) & 0xffff0000u);
}

__device__ __forceinline__ bf16x8 upack(unsigned a, unsigned b, unsigned c, unsigned d) {
    union { unsigned u[4]; bf16x8 v; } t;
    t.u[0] = a; t.u[1] = b; t.u[2] = c; t.u[3] = d;
    return t.v;
}

// ---------------------------------------------------------------------------
// prep: rne-split pack of W_m(+bias col), W_e (K->16), final_w (rows->16)
// ---------------------------------------------------------------------------
__global__ __launch_bounds__(256) void prep_kernel(
    const float* __restrict__ Wm, const float* __restrict__ bm,
    const float* __restrict__ We, const float* __restrict__ fw,
    unsigned short* __restrict__ WmPh, unsigned short* __restrict__ WmPl,
    unsigned short* __restrict__ WePh, unsigned short* __restrict__ WePl,
    unsigned short* __restrict__ FwPh, unsigned short* __restrict__ FwPl)
{
    int i = blockIdx.x * 256 + threadIdx.x;
    if (i < CHPAD * KPAD) {                       // WmP[160][144]
        int c = i / KPAD, k = i - c * KPAD;
        float v = 0.f;
        if (c < CAT) {
            if (k < CAT) v = Wm[c * CAT + k];
            else if (k == CAT) v = bm[c];         // bias column (pairs with m==1.0)
        }
        unsigned short h = f32_bf16_rne(v);
        WmPh[i] = h; WmPl[i] = f32_bf16_rne(v - bf16_f32(h));
    } else if (i < CHPAD * KPAD + CHPAD * 16) {   // WeP[160][16]
        int j = i - CHPAD * KPAD; int c = j >> 4, r = j & 15;
        float v = (c < CAT && r < NRBF) ? We[c * NRBF + r] : 0.f;
        unsigned short h = f32_bf16_rne(v);
        WePh[j] = h; WePl[j] = f32_bf16_rne(v - bf16_f32(h));
    } else if (i < CHPAD * KPAD + CHPAD * 16 + 16 * CHPAD) {  // FwP[16][160]
        int j = i - CHPAD * KPAD - CHPAD * 16; int r = j / CHPAD, c = j - r * CHPAD;
        float v = (r < NRBF && c < CAT) ? fw[r * CAT + c] : 0.f;
        unsigned short h = f32_bf16_rne(v);
        FwPh[j] = h; FwPl[j] = f32_bf16_rne(v - bf16_f32(h));
    }
}

// ---------------------------------------------------------------------------
// angle: s_a = dot(a_sbf[a,:], colsum(W_a)), scatter-add into sum_s[kj]
// ---------------------------------------------------------------------------
__global__ __launch_bounds__(256) void angle_kernel(
    const float* __restrict__ a_sbf, const int* __restrict__ kj_idx,
    const float* __restrict__ W_a, float* __restrict__ sum_s, int A)
{
    __shared__ float wsum[ADIM];
    int tid = threadIdx.x;
    if (tid < ADIM) {
        float s = 0.f;
        #pragma unroll
        for (int b = 0; b < NBIL; ++b) s += W_a[b * ADIM + tid];
        wsum[tid] = s;
    }
    __syncthreads();

    int a = blockIdx.x * 256 + tid;
    if (a >= A) return;

    const float* row = a_sbf + (size_t)a * ADIM;
    float s = 0.f;
    #pragma unroll
    for (int d2 = 0; d2 < ADIM / 2; ++d2) {
        float2 v = *reinterpret_cast<const float2*>(row + d2 * 2);
        s += v.x * wsum[d2 * 2] + v.y * wsum[d2 * 2 + 1];
    }
    atomicAdd(&sum_s[kj_idx[a]], s);
}

// ---------------------------------------------------------------------------
// edge: 32-edge tiles, 5 waves (one 32-channel group each).
//   - m fragments loaded per-lane DIRECT from global (f32), trunc-split in regs
//   - MFMA1 (27x 32x32x16) + te (3x) -> silu*te -> mae to wave-PRIVATE LDS slice
//   - MFMA3 (6x 16x16x32) reads own slice (no barrier) -> projp (dbuf)
//   - ONE __syncthreads per tile; 192-thread cross-wave reduce -> out
// ---------------------------------------------------------------------------
__global__ __launch_bounds__(320, 4) void edge_kernel(
    const float* __restrict__ m_ji, const float* __restrict__ e_rbf,
    const unsigned short* __restrict__ WmPh, const unsigned short* __restrict__ WmPl,
    const unsigned short* __restrict__ WePh, const unsigned short* __restrict__ WePl,
    const unsigned short* __restrict__ FwPh, const unsigned short* __restrict__ FwPl,
    const float* __restrict__ sum_s, float* __restrict__ out, int E, int NT)
{
    __shared__ unsigned short maeh[32][TSTR];   // 10752 B  (wave-private column slices)
    __shared__ unsigned short mael[32][TSTR];   // 10752 B
    __shared__ float projp[2][5][32][8];        // 10240 B  -> total 31744 B

    const int tid = threadIdx.x;
    const int l   = tid & 63;
    const int wv  = __builtin_amdgcn_readfirstlane(tid >> 6);
    const int l31 = l & 31;
    const int hi5 = l >> 5;

    const unsigned short* wrh = WmPh + (size_t)(32 * wv + l31) * KPAD + hi5 * 8;
    const unsigned short* wrl = WmPl + (size_t)(32 * wv + l31) * KPAD + hi5 * 8;

    const bf16x8 weh = *reinterpret_cast<const bf16x8*>(WePh + (32 * wv + l31) * 16 + hi5 * 8);
    const bf16x8 wel = *reinterpret_cast<const bf16x8*>(WePl + (32 * wv + l31) * 16 + hi5 * 8);
    const bf16x8 fwh = *reinterpret_cast<const bf16x8*>(FwPh + (l & 15) * CHPAD + 32 * wv + (l >> 4) * 8);
    const bf16x8 fwl = *reinterpret_cast<const bf16x8*>(FwPl + (l & 15) * CHPAD + 32 * wv + (l >> 4) * 8);

    int p = 0;
    for (int t = blockIdx.x; t < NT; t += gridDim.x) {
        const int e0 = t * 32;
        const int e  = e0 + l31;
        const bool ev = e < E;
        const float* mrow = m_ji + (size_t)e * CAT;

        // ---- e_rbf fragment (per-lane, hi5==0 lanes hold rbf 0..5) -------
        bf16x8 ebh, ebl;
        {
            unsigned h0 = 0, h1 = 0, h2 = 0, q0 = 0, q1 = 0, q2 = 0;
            if (ev && hi5 == 0) {
                const float* ep = e_rbf + (size_t)e * NRBF;
                float2 r01 = *reinterpret_cast<const float2*>(ep);
                float2 r23 = *reinterpret_cast<const float2*>(ep + 2);
                float2 r45 = *reinterpret_cast<const float2*>(ep + 4);
                split_pack(r01.x, r01.y, h0, q0);
                split_pack(r23.x, r23.y, h1, q1);
                split_pack(r45.x, r45.y, h2, q2);
            }
            ebh = upack(h0, h1, h2, 0);
            ebl = upack(q0, q1, q2, 0);
        }

        f32x16 acc  = {0,0,0,0,0,0,0,0,0,0,0,0,0,0,0,0};
        f32x16 acct = {0,0,0,0,0,0,0,0,0,0,0,0,0,0,0,0};

        // ---- MFMA1: x = Wm.m (+bias), direct-global B frags --------------
        #pragma unroll
        for (int ks = 0; ks < 9; ++ks) {
            float v[8];
            if (ks < 8) {
                if (ev) {
                    const float* p4 = mrow + ks * 16 + hi5 * 8;
                    #pragma unroll
                    for (int j = 0; j < 4; ++j) {
                        float2 t2 = *reinterpret_cast<const float2*>(p4 + 2 * j);
                        v[2 * j] = t2.x; v[2 * j + 1] = t2.y;
                    }
                } else {
                    #pragma unroll
                    for (int j = 0; j < 8; ++j) v[j] = 0.f;
                }
            } else {
                // k = 128..135 (hi5==0) or 136..143 (hi5==1, all pad)
                if (ev && hi5 == 0) {
                    const float* p4 = mrow + 128;
                    float2 a01 = *reinterpret_cast<const float2*>(p4);
                    float2 a23 = *reinterpret_cast<const float2*>(p4 + 2);
                    float2 a45 = *reinterpret_cast<const float2*>(p4 + 4);
                    v[0] = a01.x; v[1] = a01.y; v[2] = a23.x; v[3] = a23.y;
                    v[4] = a45.x; v[5] = a45.y; v[6] = 1.f; v[7] = 0.f;  // bias partner
                } else {
                    #pragma unroll
                    for (int j = 0; j < 8; ++j) v[j] = 0.f;
                }
            }
            unsigned H[4], L[4];
            #pragma unroll
            for (int j = 0; j < 4; ++j) split_pack(v[2 * j], v[2 * j + 1], H[j], L[j]);
            bf16x8 bh = upack(H[0], H[1], H[2], H[3]);
            bf16x8 bl = upack(L[0], L[1], L[2], L[3]);
            bf16x8 ah = *reinterpret_cast<const bf16x8*>(wrh + ks * 16);
            bf16x8 al = *reinterpret_cast<const bf16x8*>(wrl + ks * 16);
            acc = __builtin_amdgcn_mfma_f32_32x32x16_bf16(ah, bh, acc, 0, 0, 0);
            acc = __builtin_amdgcn_mfma_f32_32x32x16_bf16(al, bh, acc, 0, 0, 0);
            acc = __builtin_amdgcn_mfma_f32_32x32x16_bf16(ah, bl, acc, 0, 0, 0);
        }
        // ---- te = We . eb -------------------------------------------------
        acct = __builtin_amdgcn_mfma_f32_32x32x16_bf16(weh, ebh, acct, 0, 0, 0);
        acct = __builtin_amdgcn_mfma_f32_32x32x16_bf16(wel, ebh, acct, 0, 0, 0);
        acct = __builtin_amdgcn_mfma_f32_32x32x16_bf16(weh, ebl, acct, 0, 0, 0);

        // ---- mae = silu(x)*te -> split -> wave-private LDS slice ----------
        #pragma unroll
        for (int q = 0; q < 4; ++q) {
            float mz[4];
            #pragma unroll
            for (int i = 0; i < 4; ++i) {
                float x  = acc[q * 4 + i];
                float sg = x / (1.f + __expf(-x));
                mz[i] = sg * acct[q * 4 + i];
            }
            unsigned h0, h1, q0, q1;
            split_pack(mz[0], mz[1], h0, q0);
            split_pack(mz[2], mz[3], h1, q1);
            const int cq = 32 * wv + 8 * q + 4 * hi5;
            *reinterpret_cast<uint2*>(&maeh[l31][cq]) = make_uint2(h0, h1);
            *reinterpret_cast<uint2*>(&mael[l31][cq]) = make_uint2(q0, q1);
        }

        // ---- MFMA3: wave reads ONLY its own slice (no barrier needed) -----
        #pragma unroll
        for (int nt = 0; nt < 2; ++nt) {
            f32x4 a3 = {0, 0, 0, 0};
            const int mr = nt * 16 + (l & 15);
            bf16x8 bh = *reinterpret_cast<const bf16x8*>(&maeh[mr][32 * wv + (l >> 4) * 8]);
            bf16x8 bl = *reinterpret_cast<const bf16x8*>(&mael[mr][32 * wv + (l >> 4) * 8]);
            a3 = __builtin_amdgcn_mfma_f32_16x16x32_bf16(fwh, bh, a3, 0, 0, 0);
            a3 = __builtin_amdgcn_mfma_f32_16x16x32_bf16(fwl, bh, a3, 0, 0, 0);
            a3 = __builtin_amdgcn_mfma_f32_16x16x32_bf16(fwh, bl, a3, 0, 0, 0);
            const int g4 = l >> 4, es = nt * 16 + (l & 15);
            if (g4 == 0) {
                *reinterpret_cast<f32x4*>(&projp[p][wv][es][0]) = a3;   // rows 0-3
            } else if (g4 == 1) {
                projp[p][wv][es][4] = a3[0];                            // rows 4-5
                projp[p][wv][es][5] = a3[1];
            }
        }

        __syncthreads();   // the ONE barrier: projp[p] complete

        // ---- cross-wave reduce + scale + store (projp double-buffered) ---
        if (tid < 192) {
            const int es = tid / 6, r = tid - es * 6;
            const int eo = e0 + es;
            if (eo < E) {
                float vsum = projp[p][0][es][r] + projp[p][1][es][r] + projp[p][2][es][r]
                           + projp[p][3][es][r] + projp[p][4][es][r];
                out[(size_t)eo * NRBF + r] = vsum * sum_s[eo];
            }
        }
        p ^= 1;
    }
}

// ---------------------------------------------------------------------------
extern "C" void kernel_launch(void* const* d_in, const int* in_sizes, int n_in,
                              void* d_out, int out_size, void* d_ws, size_t ws_size,
                              hipStream_t stream)
{
    const float* m_ji    = (const float*)d_in[0];
    // d_in[1] nbr_list, d_in[2] angle_list: unused by the reference math
    const float* e_rbf   = (const float*)d_in[3];
    const float* a_sbf   = (const float*)d_in[4];
    const int*   kj_idx  = (const int*)  d_in[5];
    const float* W_m     = (const float*)d_in[6];
    const float* b_m     = (const float*)d_in[7];
    const float* W_e     = (const float*)d_in[8];
    const float* W_a     = (const float*)d_in[9];
    const float* final_w = (const float*)d_in[10];
    float* out = (float*)d_out;

    const int E  = in_sizes[0] / CAT;
    const int A  = in_sizes[5];
    const int NT = (E + 31) / 32;

    // workspace layout
    char* ws = (char*)d_ws;
    float* sum_s = (float*)ws;
    size_t off = ((size_t)E * 4 + 255) & ~(size_t)255;
    unsigned short* WmPh = (unsigned short*)(ws + off); off += CHPAD * KPAD * 2;
    unsigned short* WmPl = (unsigned short*)(ws + off); off += CHPAD * KPAD * 2;
    unsigned short* WePh = (unsigned short*)(ws + off); off += CHPAD * 16 * 2;
    unsigned short* WePl = (unsigned short*)(ws + off); off += CHPAD * 16 * 2;
    unsigned short* FwPh = (unsigned short*)(ws + off); off += 16 * CHPAD * 2;
    unsigned short* FwPl = (unsigned short*)(ws + off); off += 16 * CHPAD * 2;

    hipMemsetAsync(sum_s, 0, (size_t)E * sizeof(float), stream);

    const int prep_n = CHPAD * KPAD + CHPAD * 16 + 16 * CHPAD;
    prep_kernel<<<(prep_n + 255) / 256, 256, 0, stream>>>(
        W_m, b_m, W_e, final_w, WmPh, WmPl, WePh, WePl, FwPh, FwPl);
    angle_kernel<<<(A + 255) / 256, 256, 0, stream>>>(a_sbf, kj_idx, W_a, sum_s, A);

    int grid = 2048; if (grid > NT) grid = NT;
    edge_kernel<<<grid, 320, 0, stream>>>(m_ji, e_rbf, WmPh, WmPl, WePh, WePl,
                                          FwPh, FwPl, sum_s, out, E, NT);
}

// Round 5
// 262.867 us; speedup vs baseline: 3.2532x; 1.2233x over previous
//
#include <hip/hip_runtime.h>
#include <math.h>

#define CAT    134
#define NRBF   6
#define ADIM   42
#define NBIL   8
#define KPAD   144      // 9 k-steps of 16 (k=134 is the bias column)
#define CHPAD  160      // 5 waves x 32 channels
#define MSTR   152      // m LDS row stride (shorts): 304 B, 16B-aligned, 8-lane bank period
#define TSTR   168      // mae row stride (shorts): 336 B, 16B-aligned, 8-lane bank period
#define TE     32       // edges per tile
#define M2     (TE * 67)   // float2 count of one m tile (32*134/2)

typedef __bf16 bf16x8 __attribute__((ext_vector_type(8)));
typedef float  f32x16 __attribute__((ext_vector_type(16)));
typedef float  f32x4  __attribute__((ext_vector_type(4)));

__device__ __forceinline__ unsigned short f32_bf16_rne(float x) {
    union { float f; unsigned u; } v; v.f = x;
    unsigned u = v.u;
    u += 0x7FFFu + ((u >> 16) & 1u);
    return (unsigned short)(u >> 16);
}
__device__ __forceinline__ float bf16_f32(unsigned short h) {
    union { float f; unsigned u; } v; v.u = ((unsigned)h) << 16;
    return v.f;
}
// trunc split: a = hi + lo, |err| ~ 2^-17 |a|
__device__ __forceinline__ void split_pack(float a, float b, unsigned& ph, unsigned& pl) {
    unsigned ua = __float_as_uint(a), ub = __float_as_uint(b);
    ph = (ua >> 16) | (ub & 0xffff0000u);
    float ra = a - __uint_as_float(ua & 0xffff0000u);
    float rb = b - __uint_as_float(ub & 0xffff0000u);
    pl = (__float_as_uint(ra) >> 16) | (__float_as_uint(rb) & 0xffff0000u);
}
__device__ __forceinline__ bf16x8 upack(unsigned a, unsigned b, unsigned c, unsigned d) {
    union { unsigned u[4]; bf16x8 v; } t;
    t.u[0] = a; t.u[1] = b; t.u[2] = c; t.u[3] = d;
    return t.v;
}

// ---------------------------------------------------------------------------
// prep: pack weights into FRAGMENT-MAJOR layout so in-kernel fragment loads
// are fully coalesced:  WF[((wv*9+ks)*64+lane)*16 + {j | 8+j}] = {hi | lo}
// ---------------------------------------------------------------------------
__global__ __launch_bounds__(256) void prep_kernel(
    const float* __restrict__ Wm, const float* __restrict__ bm,
    const float* __restrict__ We, const float* __restrict__ fw,
    unsigned short* __restrict__ WF, unsigned short* __restrict__ WeF,
    unsigned short* __restrict__ FwF)
{
    int i = blockIdx.x * 256 + threadIdx.x;
    if (i < CHPAD * KPAD) {                                  // W_m (+bias col)
        int c = i / KPAD, k = i - c * KPAD;
        float v = 0.f;
        if (c < CAT) {
            if (k < CAT) v = Wm[c * CAT + k];
            else if (k == CAT) v = bm[c];
        }
        unsigned short h = f32_bf16_rne(v);
        unsigned short l = f32_bf16_rne(v - bf16_f32(h));
        int wv = c >> 5, l31 = c & 31, ks = k >> 4;
        int lane = ((k >> 3) & 1) * 32 + l31, j = k & 7;
        size_t idx = ((size_t)(wv * 9 + ks) * 64 + lane) * 16 + j;
        WF[idx] = h; WF[idx + 8] = l;
    } else if (i < CHPAD * KPAD + CHPAD * 16) {              // W_e (K -> 16)
        int j2 = i - CHPAD * KPAD; int c = j2 >> 4, r = j2 & 15;
        float v = (c < CAT && r < NRBF) ? We[c * NRBF + r] : 0.f;
        unsigned short h = f32_bf16_rne(v);
        unsigned short l = f32_bf16_rne(v - bf16_f32(h));
        int wv = c >> 5, l31 = c & 31;
        int lane = (r >> 3) * 32 + l31, j = r & 7;
        size_t idx = ((size_t)wv * 64 + lane) * 16 + j;
        WeF[idx] = h; WeF[idx + 8] = l;
    } else if (i < CHPAD * KPAD + CHPAD * 16 + 16 * CHPAD) { // final_w (16 rows)
        int j3 = i - CHPAD * KPAD - CHPAD * 16;
        int r = j3 / CHPAD, c = j3 - r * CHPAD;
        float v = (r < NRBF && c < CAT) ? fw[r * CAT + c] : 0.f;
        unsigned short h = f32_bf16_rne(v);
        unsigned short l = f32_bf16_rne(v - bf16_f32(h));
        int wv = c >> 5, kk = c & 31;
        int lane = (kk >> 3) * 16 + r, j = kk & 7;
        size_t idx = ((size_t)wv * 64 + lane) * 16 + j;
        FwF[idx] = h; FwF[idx + 8] = l;
    }
}

// ---------------------------------------------------------------------------
// angle: s_a = dot(a_sbf[a,:], colsum(W_a)), scatter-add into sum_s[kj]
// ---------------------------------------------------------------------------
__global__ __launch_bounds__(256) void angle_kernel(
    const float* __restrict__ a_sbf, const int* __restrict__ kj_idx,
    const float* __restrict__ W_a, float* __restrict__ sum_s, int A)
{
    __shared__ float wsum[ADIM];
    int tid = threadIdx.x;
    if (tid < ADIM) {
        float s = 0.f;
        #pragma unroll
        for (int b = 0; b < NBIL; ++b) s += W_a[b * ADIM + tid];
        wsum[tid] = s;
    }
    __syncthreads();

    int a = blockIdx.x * 256 + tid;
    if (a >= A) return;

    const float* row = a_sbf + (size_t)a * ADIM;
    float s = 0.f;
    #pragma unroll
    for (int d2 = 0; d2 < ADIM / 2; ++d2) {
        float2 v = *reinterpret_cast<const float2*>(row + d2 * 2);
        s += v.x * wsum[d2 * 2] + v.y * wsum[d2 * 2 + 1];
    }
    atomicAdd(&sum_s[kj_idx[a]], s);
}

// ---------------------------------------------------------------------------
// edge: 32-edge tiles, 5 waves. Coalesced flat staging of the contiguous
// 17 KB m-block -> convert ONCE -> split-bf16 LDS. Prefetch next tile's
// global loads under the MFMA phases (T14). 2 barriers/tile.
// ---------------------------------------------------------------------------
__global__ __launch_bounds__(320, 3) void edge_kernel(
    const float* __restrict__ m_ji, const float* __restrict__ e_rbf,
    const unsigned short* __restrict__ WF, const unsigned short* __restrict__ WeF,
    const unsigned short* __restrict__ FwF,
    const float* __restrict__ sum_s, float* __restrict__ out, int E, int NT)
{
    __shared__ unsigned short mhs[TE][MSTR];    //  9728 B
    __shared__ unsigned short mls[TE][MSTR];    //  9728 B
    __shared__ unsigned short ebh[TE][16];      //  1024 B
    __shared__ unsigned short ebl[TE][16];      //  1024 B
    __shared__ unsigned short maeh[TE][TSTR];   // 10752 B
    __shared__ unsigned short mael[TE][TSTR];   // 10752 B
    __shared__ float projp[5][TE][8];           //  5120 B  -> 48128 B total

    const int tid = threadIdx.x;
    const int l   = tid & 63;
    const int wv  = __builtin_amdgcn_readfirstlane(tid >> 6);
    const int l31 = l & 31;
    const int hi5 = l >> 5;

    // ---- persistent weight fragments (fully coalesced loads) -------------
    bf16x8 wfh[9], wfl[9];
    #pragma unroll
    for (int ks = 0; ks < 9; ++ks) {
        const unsigned short* p = WF + ((size_t)(wv * 9 + ks) * 64 + l) * 16;
        wfh[ks] = *reinterpret_cast<const bf16x8*>(p);
        wfl[ks] = *reinterpret_cast<const bf16x8*>(p + 8);
    }
    const unsigned short* pe = WeF + ((size_t)wv * 64 + l) * 16;
    const bf16x8 weh = *reinterpret_cast<const bf16x8*>(pe);
    const bf16x8 wel = *reinterpret_cast<const bf16x8*>(pe + 8);
    const unsigned short* pf = FwF + ((size_t)wv * 64 + l) * 16;
    const bf16x8 fwh = *reinterpret_cast<const bf16x8*>(pf);
    const bf16x8 fwl = *reinterpret_cast<const bf16x8*>(pf + 8);

    // ---- one-time LDS init: m bias/pad cols (134..143), eb pad (6..15) ---
    if (tid < 160) {
        int r = tid / 5, j = tid - r * 5;
        *reinterpret_cast<unsigned*>(&mhs[r][134 + 2 * j]) = (j == 0) ? 0x00003F80u : 0u;
        *reinterpret_cast<unsigned*>(&mls[r][134 + 2 * j]) = 0u;
        *reinterpret_cast<unsigned*>(&ebh[r][6 + 2 * j]) = 0u;
        *reinterpret_cast<unsigned*>(&ebl[r][6 + 2 * j]) = 0u;
    }

    // ---- prologue prefetch ------------------------------------------------
    float2 mpre[7]; float2 epre = make_float2(0.f, 0.f);
    {
        int t0 = blockIdx.x;
        if (t0 < NT) {
            const float2* mb = reinterpret_cast<const float2*>(m_ji + (size_t)t0 * TE * CAT);
            int nv2 = min(TE, E - t0 * TE) * 67;
            #pragma unroll
            for (int i = 0; i < 7; ++i) {
                int f = tid + i * 320;
                mpre[i] = (f < nv2) ? mb[f] : make_float2(0.f, 0.f);
            }
            const float2* ebp = reinterpret_cast<const float2*>(e_rbf + (size_t)t0 * TE * NRBF);
            int nve = min(TE, E - t0 * TE) * 3;
            if (tid < 96) epre = (tid < nve) ? ebp[tid] : make_float2(0.f, 0.f);
        }
    }

    for (int t = blockIdx.x; t < NT; t += gridDim.x) {
        const int e0 = t * TE;

        // ---- convert prefetched tile -> split-bf16 LDS (ONCE per value) --
        #pragma unroll
        for (int i = 0; i < 7; ++i) {
            int f = tid + i * 320;
            if (f < M2) {
                int r = f / 67, c = f - r * 67;
                unsigned h, lo2; split_pack(mpre[i].x, mpre[i].y, h, lo2);
                *reinterpret_cast<unsigned*>(&mhs[r][2 * c]) = h;
                *reinterpret_cast<unsigned*>(&mls[r][2 * c]) = lo2;
            }
        }
        if (tid < 96) {
            int r = tid / 3, j = tid - r * 3;
            unsigned h, lo2; split_pack(epre.x, epre.y, h, lo2);
            *reinterpret_cast<unsigned*>(&ebh[r][2 * j]) = h;
            *reinterpret_cast<unsigned*>(&ebl[r][2 * j]) = lo2;
        }
        __syncthreads();   // barrier A: tile staged

        // ---- issue next tile's global loads (ride under MFMA phases) -----
        {
            int tn = t + gridDim.x;
            if (tn < NT) {
                const float2* mb = reinterpret_cast<const float2*>(m_ji + (size_t)tn * TE * CAT);
                int nv2 = min(TE, E - tn * TE) * 67;
                #pragma unroll
                for (int i = 0; i < 7; ++i) {
                    int f = tid + i * 320;
                    mpre[i] = (f < nv2) ? mb[f] : make_float2(0.f, 0.f);
                }
                const float2* ebp = reinterpret_cast<const float2*>(e_rbf + (size_t)tn * TE * NRBF);
                int nve = min(TE, E - tn * TE) * 3;
                if (tid < 96) epre = (tid < nve) ? ebp[tid] : make_float2(0.f, 0.f);
            }
        }

        // ---- MFMA1: x = Wm.m (+bias) -------------------------------------
        f32x16 acc  = {0,0,0,0,0,0,0,0,0,0,0,0,0,0,0,0};
        f32x16 acct = {0,0,0,0,0,0,0,0,0,0,0,0,0,0,0,0};
        #pragma unroll
        for (int ks = 0; ks < 9; ++ks) {
            bf16x8 bh = *reinterpret_cast<const bf16x8*>(&mhs[l31][ks * 16 + hi5 * 8]);
            bf16x8 bl = *reinterpret_cast<const bf16x8*>(&mls[l31][ks * 16 + hi5 * 8]);
            acc = __builtin_amdgcn_mfma_f32_32x32x16_bf16(wfh[ks], bh, acc, 0, 0, 0);
            acc = __builtin_amdgcn_mfma_f32_32x32x16_bf16(wfl[ks], bh, acc, 0, 0, 0);
            acc = __builtin_amdgcn_mfma_f32_32x32x16_bf16(wfh[ks], bl, acc, 0, 0, 0);
        }
        // ---- te = We . eb ------------------------------------------------
        {
            bf16x8 bh = *reinterpret_cast<const bf16x8*>(&ebh[l31][hi5 * 8]);
            bf16x8 bl = *reinterpret_cast<const bf16x8*>(&ebl[l31][hi5 * 8]);
            acct = __builtin_amdgcn_mfma_f32_32x32x16_bf16(weh, bh, acct, 0, 0, 0);
            acct = __builtin_amdgcn_mfma_f32_32x32x16_bf16(wel, bh, acct, 0, 0, 0);
            acct = __builtin_amdgcn_mfma_f32_32x32x16_bf16(weh, bl, acct, 0, 0, 0);
        }

        // ---- mae = silu(x)*te -> split -> wave-private LDS slice ---------
        #pragma unroll
        for (int q = 0; q < 4; ++q) {
            float mz[4];
            #pragma unroll
            for (int i = 0; i < 4; ++i) {
                float x  = acc[q * 4 + i];
                float sg = x / (1.f + __expf(-x));
                mz[i] = sg * acct[q * 4 + i];
            }
            unsigned h0, h1, q0, q1;
            split_pack(mz[0], mz[1], h0, q0);
            split_pack(mz[2], mz[3], h1, q1);
            const int cq = 32 * wv + 8 * q + 4 * hi5;
            *reinterpret_cast<uint2*>(&maeh[l31][cq]) = make_uint2(h0, h1);
            *reinterpret_cast<uint2*>(&mael[l31][cq]) = make_uint2(q0, q1);
        }

        // ---- MFMA3: wave reads ONLY its own mae slice (no barrier) -------
        #pragma unroll
        for (int nt = 0; nt < 2; ++nt) {
            f32x4 a3 = {0, 0, 0, 0};
            const int mr = nt * 16 + (l & 15);
            bf16x8 bh = *reinterpret_cast<const bf16x8*>(&maeh[mr][32 * wv + (l >> 4) * 8]);
            bf16x8 bl = *reinterpret_cast<const bf16x8*>(&mael[mr][32 * wv + (l >> 4) * 8]);
            a3 = __builtin_amdgcn_mfma_f32_16x16x32_bf16(fwh, bh, a3, 0, 0, 0);
            a3 = __builtin_amdgcn_mfma_f32_16x16x32_bf16(fwl, bh, a3, 0, 0, 0);
            a3 = __builtin_amdgcn_mfma_f32_16x16x32_bf16(fwh, bl, a3, 0, 0, 0);
            const int g4 = l >> 4, es = nt * 16 + (l & 15);
            if (g4 == 0) {
                *reinterpret_cast<f32x4*>(&projp[wv][es][0]) = a3;   // rows 0-3
            } else if (g4 == 1) {
                projp[wv][es][4] = a3[0];                            // rows 4-5
                projp[wv][es][5] = a3[1];
            }
        }
        __syncthreads();   // barrier B: projp complete, LDS m free to reuse

        // ---- cross-wave reduce + scale + store ---------------------------
        if (tid < 192) {
            const int es = tid / 6, r = tid - es * 6;
            const int eo = e0 + es;
            if (eo < E) {
                float vsum = projp[0][es][r] + projp[1][es][r] + projp[2][es][r]
                           + projp[3][es][r] + projp[4][es][r];
                out[(size_t)eo * NRBF + r] = vsum * sum_s[eo];
            }
        }
    }
}

// ---------------------------------------------------------------------------
extern "C" void kernel_launch(void* const* d_in, const int* in_sizes, int n_in,
                              void* d_out, int out_size, void* d_ws, size_t ws_size,
                              hipStream_t stream)
{
    const float* m_ji    = (const float*)d_in[0];
    // d_in[1] nbr_list, d_in[2] angle_list: unused by the reference math
    const float* e_rbf   = (const float*)d_in[3];
    const float* a_sbf   = (const float*)d_in[4];
    const int*   kj_idx  = (const int*)  d_in[5];
    const float* W_m     = (const float*)d_in[6];
    const float* b_m     = (const float*)d_in[7];
    const float* W_e     = (const float*)d_in[8];
    const float* W_a     = (const float*)d_in[9];
    const float* final_w = (const float*)d_in[10];
    float* out = (float*)d_out;

    const int E  = in_sizes[0] / CAT;
    const int A  = in_sizes[5];
    const int NT = (E + TE - 1) / TE;

    // workspace layout
    char* ws = (char*)d_ws;
    float* sum_s = (float*)ws;
    size_t off = ((size_t)E * 4 + 255) & ~(size_t)255;
    unsigned short* WF  = (unsigned short*)(ws + off); off += (size_t)5 * 9 * 64 * 16 * 2;
    unsigned short* WeF = (unsigned short*)(ws + off); off += (size_t)5 * 64 * 16 * 2;
    unsigned short* FwF = (unsigned short*)(ws + off); off += (size_t)5 * 64 * 16 * 2;

    hipMemsetAsync(sum_s, 0, (size_t)E * sizeof(float), stream);

    const int prep_n = CHPAD * KPAD + CHPAD * 16 + 16 * CHPAD;
    prep_kernel<<<(prep_n + 255) / 256, 256, 0, stream>>>(
        W_m, b_m, W_e, final_w, WF, WeF, FwF);
    angle_kernel<<<(A + 255) / 256, 256, 0, stream>>>(a_sbf, kj_idx, W_a, sum_s, A);

    int grid = 768; if (grid > NT) grid = NT;
    edge_kernel<<<grid, 320, 0, stream>>>(m_ji, e_rbf, WF, WeF, FwF,
                                          sum_s, out, E, NT);
}

// Round 7
// 224.411 us; speedup vs baseline: 3.8106x; 1.1714x over previous
//
#include <hip/hip_runtime.h>
#include <math.h>

#define CAT    134
#define NRBF   6
#define ADIM   42
#define NBIL   8
#define KPAD   144      // 9 k-steps of 16 (k=134 is the bias column)
#define CHPAD  160      // 5 waves x 32 channels
#define MSTR   152      // m LDS row stride (shorts): 304 B, 16B-aligned
#define TSTR   168      // mae row stride (shorts): 336 B, 16B-aligned
#define TE     32       // edges per tile
#define M2     (TE * 67)   // float2 count of one m tile (32*134/2)

typedef __bf16 bf16x8 __attribute__((ext_vector_type(8)));
typedef float  f32x16 __attribute__((ext_vector_type(16)));
typedef float  f32x4  __attribute__((ext_vector_type(4)));

__device__ __forceinline__ unsigned short f32_bf16_rne(float x) {
    union { float f; unsigned u; } v; v.f = x;
    unsigned u = v.u;
    u += 0x7FFFu + ((u >> 16) & 1u);
    return (unsigned short)(u >> 16);
}
__device__ __forceinline__ float bf16_f32(unsigned short h) {
    union { float f; unsigned u; } v; v.u = ((unsigned)h) << 16;
    return v.f;
}
// trunc split: a = hi + lo, |err| ~ 2^-17 |a|
__device__ __forceinline__ void split_pack(float a, float b, unsigned& ph, unsigned& pl) {
    unsigned ua = __float_as_uint(a), ub = __float_as_uint(b);
    ph = (ua >> 16) | (ub & 0xffff0000u);
    float ra = a - __uint_as_float(ua & 0xffff0000u);
    float rb = b - __uint_as_float(ub & 0xffff0000u);
    pl = (__float_as_uint(ra) >> 16) | (__float_as_uint(rb) & 0xffff0000u);
}

// ---------------------------------------------------------------------------
// prep: pack weights into FRAGMENT-MAJOR layout so in-kernel fragment loads
// are fully coalesced:  WF[((wv*9+ks)*64+lane)*16 + {j | 8+j}] = {hi | lo}
// ---------------------------------------------------------------------------
__global__ __launch_bounds__(256) void prep_kernel(
    const float* __restrict__ Wm, const float* __restrict__ bm,
    const float* __restrict__ We, const float* __restrict__ fw,
    unsigned short* __restrict__ WF, unsigned short* __restrict__ WeF,
    unsigned short* __restrict__ FwF)
{
    int i = blockIdx.x * 256 + threadIdx.x;
    if (i < CHPAD * KPAD) {                                  // W_m (+bias col)
        int c = i / KPAD, k = i - c * KPAD;
        float v = 0.f;
        if (c < CAT) {
            if (k < CAT) v = Wm[c * CAT + k];
            else if (k == CAT) v = bm[c];
        }
        unsigned short h = f32_bf16_rne(v);
        unsigned short l = f32_bf16_rne(v - bf16_f32(h));
        int wv = c >> 5, l31 = c & 31, ks = k >> 4;
        int lane = ((k >> 3) & 1) * 32 + l31, j = k & 7;
        size_t idx = ((size_t)(wv * 9 + ks) * 64 + lane) * 16 + j;
        WF[idx] = h; WF[idx + 8] = l;
    } else if (i < CHPAD * KPAD + CHPAD * 16) {              // W_e (K -> 16)
        int j2 = i - CHPAD * KPAD; int c = j2 >> 4, r = j2 & 15;
        float v = (c < CAT && r < NRBF) ? We[c * NRBF + r] : 0.f;
        unsigned short h = f32_bf16_rne(v);
        unsigned short l = f32_bf16_rne(v - bf16_f32(h));
        int wv = c >> 5, l31 = c & 31;
        int lane = (r >> 3) * 32 + l31, j = r & 7;
        size_t idx = ((size_t)wv * 64 + lane) * 16 + j;
        WeF[idx] = h; WeF[idx + 8] = l;
    } else if (i < CHPAD * KPAD + CHPAD * 16 + 16 * CHPAD) { // final_w (16 rows)
        int j3 = i - CHPAD * KPAD - CHPAD * 16;
        int r = j3 / CHPAD, c = j3 - r * CHPAD;
        float v = (r < NRBF && c < CAT) ? fw[r * CAT + c] : 0.f;
        unsigned short h = f32_bf16_rne(v);
        unsigned short l = f32_bf16_rne(v - bf16_f32(h));
        int wv = c >> 5, kk = c & 31;
        int lane = (kk >> 3) * 16 + r, j = kk & 7;
        size_t idx = ((size_t)wv * 64 + lane) * 16 + j;
        FwF[idx] = h; FwF[idx + 8] = l;
    }
}

// ---------------------------------------------------------------------------
// angle: s_a = dot(a_sbf[a,:], colsum(W_a)), scatter-add into sum_s[kj]
// ---------------------------------------------------------------------------
__global__ __launch_bounds__(256) void angle_kernel(
    const float* __restrict__ a_sbf, const int* __restrict__ kj_idx,
    const float* __restrict__ W_a, float* __restrict__ sum_s, int A)
{
    __shared__ float wsum[ADIM];
    int tid = threadIdx.x;
    if (tid < ADIM) {
        float s = 0.f;
        #pragma unroll
        for (int b = 0; b < NBIL; ++b) s += W_a[b * ADIM + tid];
        wsum[tid] = s;
    }
    __syncthreads();

    int a = blockIdx.x * 256 + tid;
    if (a >= A) return;

    const float* row = a_sbf + (size_t)a * ADIM;
    float s = 0.f;
    #pragma unroll
    for (int d2 = 0; d2 < ADIM / 2; ++d2) {
        float2 v = *reinterpret_cast<const float2*>(row + d2 * 2);
        s += v.x * wsum[d2 * 2] + v.y * wsum[d2 * 2 + 1];
    }
    atomicAdd(&sum_s[kj_idx[a]], s);
}

// Zero-instruction opaque pin: after this, the values' defining op is the asm,
// so the compiler cannot rematerialize the loads that produced them.
#define PIN_WEIGHTS()                                                          \
    asm volatile("" :                                                         \
        "+v"(wfh[0]), "+v"(wfh[1]), "+v"(wfh[2]), "+v"(wfh[3]), "+v"(wfh[4]), \
        "+v"(wfh[5]), "+v"(wfh[6]), "+v"(wfh[7]), "+v"(wfh[8]),               \
        "+v"(wfl[0]), "+v"(wfl[1]), "+v"(wfl[2]), "+v"(wfl[3]), "+v"(wfl[4]), \
        "+v"(wfl[5]), "+v"(wfl[6]), "+v"(wfl[7]), "+v"(wfl[8]),               \
        "+v"(weh), "+v"(wel), "+v"(fwh), "+v"(fwl))

// ---------------------------------------------------------------------------
// edge: 32-edge tiles, 5 waves. Weight fragments loaded once (compiler-
// tracked loads) then pinned in VGPRs via opaque identity asm. Main loop:
// ds_read + MFMA + VALU only; next tile's m prefetched under the MFMA phases.
// 2 barriers/tile.
// ---------------------------------------------------------------------------
__global__ __launch_bounds__(320, 3) void edge_kernel(
    const float* __restrict__ m_ji, const float* __restrict__ e_rbf,
    const unsigned short* __restrict__ WF, const unsigned short* __restrict__ WeF,
    const unsigned short* __restrict__ FwF,
    const float* __restrict__ sum_s, float* __restrict__ out, int E, int NT)
{
    __shared__ unsigned short mhs[TE][MSTR];    //  9728 B
    __shared__ unsigned short mls[TE][MSTR];    //  9728 B
    __shared__ unsigned short ebh[TE][16];      //  1024 B
    __shared__ unsigned short ebl[TE][16];      //  1024 B
    __shared__ unsigned short maeh[TE][TSTR];   // 10752 B
    __shared__ unsigned short mael[TE][TSTR];   // 10752 B
    __shared__ float projp[5][TE][8];           //  5120 B  -> 48128 B total

    const int tid = threadIdx.x;
    const int l   = tid & 63;
    const int wv  = __builtin_amdgcn_readfirstlane(tid >> 6);
    const int l31 = l & 31;
    const int hi5 = l >> 5;

    // ---- persistent weight fragments (normal loads, then opaque pin) -----
    bf16x8 wfh[9], wfl[9];
    #pragma unroll
    for (int ks = 0; ks < 9; ++ks) {
        const unsigned short* p = WF + ((size_t)(wv * 9 + ks) * 64 + l) * 16;
        wfh[ks] = *reinterpret_cast<const bf16x8*>(p);
        wfl[ks] = *reinterpret_cast<const bf16x8*>(p + 8);
    }
    const unsigned short* pe = WeF + ((size_t)wv * 64 + l) * 16;
    bf16x8 weh = *reinterpret_cast<const bf16x8*>(pe);
    bf16x8 wel = *reinterpret_cast<const bf16x8*>(pe + 8);
    const unsigned short* pf = FwF + ((size_t)wv * 64 + l) * 16;
    bf16x8 fwh = *reinterpret_cast<const bf16x8*>(pf);
    bf16x8 fwl = *reinterpret_cast<const bf16x8*>(pf + 8);
    PIN_WEIGHTS();

    // ---- one-time LDS init: m bias/pad cols (134..143), eb pad (6..15) ---
    if (tid < 160) {
        int r = tid / 5, j = tid - r * 5;
        *reinterpret_cast<unsigned*>(&mhs[r][134 + 2 * j]) = (j == 0) ? 0x00003F80u : 0u;
        *reinterpret_cast<unsigned*>(&mls[r][134 + 2 * j]) = 0u;
        *reinterpret_cast<unsigned*>(&ebh[r][6 + 2 * j]) = 0u;
        *reinterpret_cast<unsigned*>(&ebl[r][6 + 2 * j]) = 0u;
    }

    // ---- prologue prefetch ------------------------------------------------
    float2 mpre[7]; float2 epre = make_float2(0.f, 0.f);
    {
        int t0 = blockIdx.x;
        if (t0 < NT) {
            const float2* mb = reinterpret_cast<const float2*>(m_ji + (size_t)t0 * TE * CAT);
            int nv2 = min(TE, E - t0 * TE) * 67;
            #pragma unroll
            for (int i = 0; i < 7; ++i) {
                int f = tid + i * 320;
                mpre[i] = (f < nv2) ? mb[f] : make_float2(0.f, 0.f);
            }
            const float2* ebp = reinterpret_cast<const float2*>(e_rbf + (size_t)t0 * TE * NRBF);
            int nve = min(TE, E - t0 * TE) * 3;
            if (tid < 96) epre = (tid < nve) ? ebp[tid] : make_float2(0.f, 0.f);
        }
    }

    for (int t = blockIdx.x; t < NT; t += gridDim.x) {
        const int e0 = t * TE;
        PIN_WEIGHTS();   // re-assert register residency each iteration (0 instrs)

        // ---- convert prefetched tile -> split-bf16 LDS (ONCE per value) --
        #pragma unroll
        for (int i = 0; i < 7; ++i) {
            int f = tid + i * 320;
            if (f < M2) {
                int r = f / 67, c = f - r * 67;
                unsigned h, lo2; split_pack(mpre[i].x, mpre[i].y, h, lo2);
                *reinterpret_cast<unsigned*>(&mhs[r][2 * c]) = h;
                *reinterpret_cast<unsigned*>(&mls[r][2 * c]) = lo2;
            }
        }
        if (tid < 96) {
            int r = tid / 3, j = tid - r * 3;
            unsigned h, lo2; split_pack(epre.x, epre.y, h, lo2);
            *reinterpret_cast<unsigned*>(&ebh[r][2 * j]) = h;
            *reinterpret_cast<unsigned*>(&ebl[r][2 * j]) = lo2;
        }
        __syncthreads();   // barrier A: tile staged

        // ---- issue next tile's global loads (ride under MFMA phases) -----
        {
            int tn = t + gridDim.x;
            if (tn < NT) {
                const float2* mb = reinterpret_cast<const float2*>(m_ji + (size_t)tn * TE * CAT);
                int nv2 = min(TE, E - tn * TE) * 67;
                #pragma unroll
                for (int i = 0; i < 7; ++i) {
                    int f = tid + i * 320;
                    mpre[i] = (f < nv2) ? mb[f] : make_float2(0.f, 0.f);
                }
                const float2* ebp = reinterpret_cast<const float2*>(e_rbf + (size_t)tn * TE * NRBF);
                int nve = min(TE, E - tn * TE) * 3;
                if (tid < 96) epre = (tid < nve) ? ebp[tid] : make_float2(0.f, 0.f);
            }
        }

        // ---- MFMA1: x = Wm.m (+bias) -------------------------------------
        f32x16 acc  = {0,0,0,0,0,0,0,0,0,0,0,0,0,0,0,0};
        f32x16 acct = {0,0,0,0,0,0,0,0,0,0,0,0,0,0,0,0};
        #pragma unroll
        for (int ks = 0; ks < 9; ++ks) {
            bf16x8 bh = *reinterpret_cast<const bf16x8*>(&mhs[l31][ks * 16 + hi5 * 8]);
            bf16x8 bl = *reinterpret_cast<const bf16x8*>(&mls[l31][ks * 16 + hi5 * 8]);
            acc = __builtin_amdgcn_mfma_f32_32x32x16_bf16(wfh[ks], bh, acc, 0, 0, 0);
            acc = __builtin_amdgcn_mfma_f32_32x32x16_bf16(wfl[ks], bh, acc, 0, 0, 0);
            acc = __builtin_amdgcn_mfma_f32_32x32x16_bf16(wfh[ks], bl, acc, 0, 0, 0);
        }
        // ---- te = We . eb ------------------------------------------------
        {
            bf16x8 bh = *reinterpret_cast<const bf16x8*>(&ebh[l31][hi5 * 8]);
            bf16x8 bl = *reinterpret_cast<const bf16x8*>(&ebl[l31][hi5 * 8]);
            acct = __builtin_amdgcn_mfma_f32_32x32x16_bf16(weh, bh, acct, 0, 0, 0);
            acct = __builtin_amdgcn_mfma_f32_32x32x16_bf16(wel, bh, acct, 0, 0, 0);
            acct = __builtin_amdgcn_mfma_f32_32x32x16_bf16(weh, bl, acct, 0, 0, 0);
        }

        // ---- mae = silu(x)*te -> split -> wave-private LDS slice ---------
        #pragma unroll
        for (int q = 0; q < 4; ++q) {
            float mz[4];
            #pragma unroll
            for (int i = 0; i < 4; ++i) {
                float x  = acc[q * 4 + i];
                float sg = x / (1.f + __expf(-x));
                mz[i] = sg * acct[q * 4 + i];
            }
            unsigned h0, h1, q0, q1;
            split_pack(mz[0], mz[1], h0, q0);
            split_pack(mz[2], mz[3], h1, q1);
            const int cq = 32 * wv + 8 * q + 4 * hi5;
            *reinterpret_cast<uint2*>(&maeh[l31][cq]) = make_uint2(h0, h1);
            *reinterpret_cast<uint2*>(&mael[l31][cq]) = make_uint2(q0, q1);
        }

        // ---- MFMA3: wave reads ONLY its own mae slice (no barrier) -------
        #pragma unroll
        for (int nt = 0; nt < 2; ++nt) {
            f32x4 a3 = {0, 0, 0, 0};
            const int mr = nt * 16 + (l & 15);
            bf16x8 bh = *reinterpret_cast<const bf16x8*>(&maeh[mr][32 * wv + (l >> 4) * 8]);
            bf16x8 bl = *reinterpret_cast<const bf16x8*>(&mael[mr][32 * wv + (l >> 4) * 8]);
            a3 = __builtin_amdgcn_mfma_f32_16x16x32_bf16(fwh, bh, a3, 0, 0, 0);
            a3 = __builtin_amdgcn_mfma_f32_16x16x32_bf16(fwl, bh, a3, 0, 0, 0);
            a3 = __builtin_amdgcn_mfma_f32_16x16x32_bf16(fwh, bl, a3, 0, 0, 0);
            const int g4 = l >> 4, es = nt * 16 + (l & 15);
            if (g4 == 0) {
                *reinterpret_cast<f32x4*>(&projp[wv][es][0]) = a3;   // rows 0-3
            } else if (g4 == 1) {
                projp[wv][es][4] = a3[0];                            // rows 4-5
                projp[wv][es][5] = a3[1];
            }
        }
        __syncthreads();   // barrier B: projp complete, LDS m free to reuse

        // ---- cross-wave reduce + scale + store ---------------------------
        if (tid < 192) {
            const int es = tid / 6, r = tid - es * 6;
            const int eo = e0 + es;
            if (eo < E) {
                float vsum = projp[0][es][r] + projp[1][es][r] + projp[2][es][r]
                           + projp[3][es][r] + projp[4][es][r];
                out[(size_t)eo * NRBF + r] = vsum * sum_s[eo];
            }
        }
    }
}

// ---------------------------------------------------------------------------
extern "C" void kernel_launch(void* const* d_in, const int* in_sizes, int n_in,
                              void* d_out, int out_size, void* d_ws, size_t ws_size,
                              hipStream_t stream)
{
    const float* m_ji    = (const float*)d_in[0];
    // d_in[1] nbr_list, d_in[2] angle_list: unused by the reference math
    const float* e_rbf   = (const float*)d_in[3];
    const float* a_sbf   = (const float*)d_in[4];
    const int*   kj_idx  = (const int*)  d_in[5];
    const float* W_m     = (const float*)d_in[6];
    const float* b_m     = (const float*)d_in[7];
    const float* W_e     = (const float*)d_in[8];
    const float* W_a     = (const float*)d_in[9];
    const float* final_w = (const float*)d_in[10];
    float* out = (float*)d_out;

    const int E  = in_sizes[0] / CAT;
    const int A  = in_sizes[5];
    const int NT = (E + TE - 1) / TE;

    // workspace layout
    char* ws = (char*)d_ws;
    float* sum_s = (float*)ws;
    size_t off = ((size_t)E * 4 + 255) & ~(size_t)255;
    unsigned short* WF  = (unsigned short*)(ws + off); off += (size_t)5 * 9 * 64 * 16 * 2;
    unsigned short* WeF = (unsigned short*)(ws + off); off += (size_t)5 * 64 * 16 * 2;
    unsigned short* FwF = (unsigned short*)(ws + off); off += (size_t)5 * 64 * 16 * 2;

    hipMemsetAsync(sum_s, 0, (size_t)E * sizeof(float), stream);

    const int prep_n = CHPAD * KPAD + CHPAD * 16 + 16 * CHPAD;
    prep_kernel<<<(prep_n + 255) / 256, 256, 0, stream>>>(
        W_m, b_m, W_e, final_w, WF, WeF, FwF);
    angle_kernel<<<(A + 255) / 256, 256, 0, stream>>>(a_sbf, kj_idx, W_a, sum_s, A);

    int grid = 512; if (grid > NT) grid = NT;
    edge_kernel<<<grid, 320, 0, stream>>>(m_ji, e_rbf, WF, WeF, FwF,
                                          sum_s, out, E, NT);
}